// Round 6
// baseline (1787.158 us; speedup 1.0000x reference)
//
#include <hip/hip_runtime.h>
#include <math.h>

typedef unsigned short u16;
typedef unsigned int   u32;
typedef __attribute__((ext_vector_type(8))) short bf16x8;
typedef __attribute__((ext_vector_type(4))) float f32x4;

typedef const void __attribute__((address_space(1))) gv1_t;
typedef void       __attribute__((address_space(3))) lv3_t;
#define GLL(g, l) __builtin_amdgcn_global_load_lds((gv1_t*)(g), (lv3_t*)(l), 16, 0, 0)

__device__ __forceinline__ u16 f2b(float x) {
    union { float f; u32 u; } v; v.f = x;
    u32 r = v.u + 0x7FFFu + ((v.u >> 16) & 1u);
    return (u16)(r >> 16);
}
__device__ __forceinline__ float b2f(u32 x) {
    union { u32 u; float f; } v; v.u = x << 16;
    return v.f;
}
__device__ __forceinline__ float fast_sigmoid(float x) {
    return __builtin_amdgcn_rcpf(1.0f + __builtin_amdgcn_exp2f(-x * 1.44269504f));
}
__device__ __forceinline__ float fast_tanh(float x) {
    return 2.0f * __builtin_amdgcn_rcpf(1.0f + __builtin_amdgcn_exp2f(-x * 2.88539008f)) - 1.0f;
}

// ---------------------------------------------------------------------------
// prep: f32 -> bf16 convert (adj)
// ---------------------------------------------------------------------------
__global__ void cvt_f32_bf16(const float* __restrict__ a, u16* __restrict__ o, int n) {
    for (int i = (blockIdx.x * 256 + threadIdx.x) * 4; i < n; i += gridDim.x * 256 * 4) {
        float4 v = *(const float4*)&a[i];
        uint2 pk;
        pk.x = (u32)f2b(v.x) | ((u32)f2b(v.y) << 16);
        pk.y = (u32)f2b(v.z) | ((u32)f2b(v.w) << 16);
        *(uint2*)&o[i] = pk;
    }
}

// ---------------------------------------------------------------------------
// prep: x = data + temb + semb; write Xn [b][t][n][c] bf16 and XT [(b,c)][t*1024+n]
// ---------------------------------------------------------------------------
__global__ void prep_x(const float* __restrict__ data, const float* __restrict__ temb,
                       const float* __restrict__ semb, u16* __restrict__ Xn, u16* __restrict__ XT) {
    const int n0 = blockIdx.x * 64, t = blockIdx.y, b = blockIdx.z;
    const int tid = threadIdx.x;
    __shared__ u16 lt[64][66];
#pragma unroll
    for (int p = 0; p < 4; p++) {
        int n = p * 16 + (tid >> 4);
        int c = (tid & 15) * 4;
        size_t gi = ((size_t)(b * 12 + t) * 1024 + n0 + n) * 64 + c;
        float4 v  = *(const float4*)&data[gi];
        float4 tv = *(const float4*)&temb[t * 64 + c];
        float4 sv = *(const float4*)&semb[(n0 + n) * 64 + c];
        u16 u0 = f2b(v.x + tv.x + sv.x);
        u16 u1 = f2b(v.y + tv.y + sv.y);
        u16 u2 = f2b(v.z + tv.z + sv.z);
        u16 u3 = f2b(v.w + tv.w + sv.w);
        uint2 pk; pk.x = (u32)u0 | ((u32)u1 << 16); pk.y = (u32)u2 | ((u32)u3 << 16);
        *(uint2*)&Xn[gi] = pk;
        lt[n][c + 0] = u0; lt[n][c + 1] = u1; lt[n][c + 2] = u2; lt[n][c + 3] = u3;
    }
    __syncthreads();
    const int c = tid >> 2, q = tid & 3;
    u16 u[16];
#pragma unroll
    for (int i = 0; i < 16; i++) u[i] = lt[q * 16 + i][c];
    size_t xo = ((size_t)(b * 64 + c)) * 12288 + (size_t)t * 1024 + n0 + q * 16;
    uint4 p0, p1;
    p0.x = (u32)u[0] | ((u32)u[1] << 16);  p0.y = (u32)u[2] | ((u32)u[3] << 16);
    p0.z = (u32)u[4] | ((u32)u[5] << 16);  p0.w = (u32)u[6] | ((u32)u[7] << 16);
    p1.x = (u32)u[8] | ((u32)u[9] << 16);  p1.y = (u32)u[10] | ((u32)u[11] << 16);
    p1.z = (u32)u[12] | ((u32)u[13] << 16); p1.w = (u32)u[14] | ((u32)u[15] << 16);
    *(uint4*)&XT[xo] = p0;
    *(uint4*)&XT[xo + 8] = p1;
}

// ---------------------------------------------------------------------------
// prep: fc_w [27][64][128] -> Wt [27][128][64] bf16 ; conv weights -> Wc bf16
// ---------------------------------------------------------------------------
__global__ void prep_w(const float* __restrict__ fcw, const float* __restrict__ cwl,
                       const float* __restrict__ cwr, u16* __restrict__ Wt, u16* __restrict__ Wc) {
    const int blk = blockIdx.x, tid = threadIdx.x;
    if (blk < 27) {
        const float* src = fcw + (size_t)blk * 64 * 128;
        u16* dst = Wt + (size_t)blk * 128 * 64;
        for (int e = tid; e < 8192; e += 256) {
            int c = e >> 7, f = e & 127;
            dst[f * 64 + c] = f2b(src[c * 128 + f]);
        }
    } else {
        for (int e = tid; e < 16384; e += 256) {
            int o = e >> 7, k = e & 127;
            float v = (o < 64) ? cwl[(o * 64 + (k & 63)) * 2 + (k >> 6)]
                               : cwr[((o - 64) * 64 + (k & 63)) * 2 + (k >> 6)];
            Wc[o * 128 + k] = f2b(v);
        }
    }
}

// ---------------------------------------------------------------------------
// gated dilated conv as GEMM (unchanged)
// ---------------------------------------------------------------------------
__global__ __launch_bounds__(256) void dconv_gemm(
    const u16* __restrict__ Xn, const u16* __restrict__ Wc,
    const float* __restrict__ cbl, const float* __restrict__ cbr,
    float* __restrict__ out) {
    const int n0 = blockIdx.x * 128, t = blockIdx.y, b = blockIdx.z;
    const int tid = threadIdx.x, lane = tid & 63, wid = tid >> 6;
    __shared__ u16 alds[2][128 * 32];
    const u16* base0 = Xn + (size_t)(b * 12 + t) * 1024 * 64;
    const u16* base3 = Xn + (size_t)(b * 12 + t + 3) * 1024 * 64;

    auto stage = [&](int buf, int kt) {
        int k0 = kt * 32;
#pragma unroll
        for (int q = 0; q < 2; q++) {
            int r = wid * 32 + q * 16 + (lane >> 2);
            int k = k0 + (lane & 3) * 8;
            const u16* gs = (k < 64) ? base0 + (size_t)(n0 + r) * 64 + k
                                     : base3 + (size_t)(n0 + r) * 64 + (k - 64);
            GLL(gs, &alds[buf][(wid * 32 + q * 16) * 32]);
        }
    };

    f32x4 acc[2][8] = {};
    stage(0, 0);
    __syncthreads();
    const int a_off = (wid * 32 + (lane & 15)) * 32 + (lane >> 4) * 8;
    for (int kt = 0; kt < 4; kt++) {
        int cur = kt & 1;
        if (kt < 3) stage(cur ^ 1, kt + 1);
        bf16x8 af[2];
#pragma unroll
        for (int m = 0; m < 2; m++) af[m] = *(const bf16x8*)&alds[cur][a_off + m * 16 * 32];
#pragma unroll
        for (int n = 0; n < 8; n++) {
            bf16x8 bq = *(const bf16x8*)&Wc[(n * 16 + (lane & 15)) * 128 + kt * 32 + (lane >> 4) * 8];
#pragma unroll
            for (int m = 0; m < 2; m++)
                acc[m][n] = __builtin_amdgcn_mfma_f32_16x16x32_bf16(af[m], bq, acc[m][n], 0, 0, 0);
        }
        __syncthreads();
    }
#pragma unroll
    for (int m = 0; m < 2; m++) {
#pragma unroll
        for (int n = 0; n < 4; n++) {
            int fp = n * 16 + (lane & 15);
            float b1 = cbl[fp], b2 = cbr[fp];
#pragma unroll
            for (int j = 0; j < 4; j++) {
                int row = wid * 32 + m * 16 + (lane >> 4) * 4 + j;
                float gl = acc[m][n][j] + b1;
                float gr = acc[m][n + 4][j] + b2;
                out[((size_t)(b * 9 + t) * 1024 + n0 + row) * 64 + fp] =
                    fast_sigmoid(gl) * fast_tanh(gr);
            }
        }
    }
}

// ---------------------------------------------------------------------------
// 8-phase 256x256 agg GEMM, LDS-read/MFMA OVERLAPPED, fused GLU epilogue.
// Per phase: [bar] -> [vmcnt(0) gate if needed] -> issue ds_reads for NEXT
// MFMA (ping-pong frag regs) + 2 staging GLL -> counted lgkmcnt -> 16 MFMA.
// Reads complete on the LDS pipe while MFMA crunches (they were serialized
// before: ~2300cy LDS + ~2500cy MFMA per K-tile).
// ---------------------------------------------------------------------------
#define BAR() __builtin_amdgcn_s_barrier()
#define SCB() __builtin_amdgcn_sched_barrier(0)
#define GATE0() do { asm volatile("s_waitcnt vmcnt(0)" ::: "memory"); SCB(); } while (0)
#define WAITK8 do { asm volatile("s_waitcnt lgkmcnt(8)" ::: "memory"); SCB(); } while (0)
#define WAITK4 do { asm volatile("s_waitcnt lgkmcnt(4)" ::: "memory"); SCB(); } while (0)
#define WAITK0 do { asm volatile("s_waitcnt lgkmcnt(0)" ::: "memory"); SCB(); } while (0)

template <int STAGE>
__global__ __launch_bounds__(512, 2) void agg_gemm8(
    const u16* __restrict__ A, const u16* __restrict__ Bt,
    const u16* __restrict__ Wt, const float* __restrict__ fcb,
    u16* __restrict__ P, int win0, int vbase, int nout, int ks) {
    const int tid = threadIdx.x, lane = tid & 63, wid = tid >> 6;
    const int wr = wid >> 2, wc = wid & 3;
    const int bx = blockIdx.x, by = blockIdx.y, z = blockIdx.z;
    const int rowBase = by * 256, colBase = bx * 256;
    const int win = win0 + z;
    __shared__ u16 lds[2][2][2][128 * 64];  // 128 KiB
    __shared__ float biasSm[128];
    biasSm[tid & 127] = fcb[(win * 3 + ks) * 128 + (tid & 127)];
    const u16* Az = (STAGE == 0) ? A : (A + (size_t)z * 2048 * 4096);

    const int srow = lane >> 3;
    const int skb  = 8 * ((lane & 7) ^ srow);

    // one GLL stages 8 waves x 8 rows = 64 rows (quarter): s in {0,1}
    auto stageA = [&](int buf, int half, int s, int kt) {
        int r0 = s * 64 + wid * 8;
        int row_g = rowBase + half * 128 + r0 + srow;
        const u16* src;
        if (STAGE == 0) {
            int k = kt * 64 + skb;
            src = Az + (size_t)row_g * 12288 + (size_t)(win + (k >> 10)) * 1024 + (k & 1023);
        } else {
            src = Az + (size_t)row_g * 4096 + kt * 64 + skb;
        }
        GLL(src, &lds[buf][0][half][r0 * 64]);
    };
    auto stageB = [&](int buf, int half, int s, int kt) {
        int r0 = s * 64 + wid * 8;
        int col_g = vbase + colBase + half * 128 + r0 + srow;
        GLL(Bt + (size_t)col_g * 4096 + kt * 64 + skb, &lds[buf][1][half][r0 * 64]);
    };

    f32x4 acc[8][4] = {};
    bf16x8 aP[4], aQ[4], bP[4], bQ[4];  // ping-pong fragment sets

#define RD_A(dst, buf, mb, kk)                                                \
    _Pragma("unroll") for (int mm = 0; mm < 4; mm++) {                        \
        int r = ((mb) + mm) * 16 + (lane & 15);                               \
        int hw = ((kk) * 32 + (lane >> 4) * 8) ^ ((r & 7) << 3);              \
        dst[mm] = *(const bf16x8*)&lds[buf][0][wr][r * 64 + hw];              \
    }
#define RD_B(dst, buf, kk)                                                    \
    _Pragma("unroll") for (int nn = 0; nn < 4; nn++) {                        \
        int r = (wc & 1) * 64 + nn * 16 + (lane & 15);                        \
        int hw = ((kk) * 32 + (lane >> 4) * 8) ^ ((r & 7) << 3);              \
        dst[nn] = *(const bf16x8*)&lds[buf][1][wc >> 1][r * 64 + hw];         \
    }
#define MM(mb, Af, Bf)                                                        \
    __builtin_amdgcn_s_setprio(1);                                            \
    _Pragma("unroll") for (int mm = 0; mm < 4; mm++)                          \
    _Pragma("unroll") for (int nn = 0; nn < 4; nn++)                          \
        acc[(mb) + mm][nn] = __builtin_amdgcn_mfma_f32_16x16x32_bf16(         \
            Af[mm], Bf[nn], acc[(mb) + mm][nn], 0, 0, 0);                     \
    __builtin_amdgcn_s_setprio(0);

    // Standard tile: read-buf RB; stages tile TS into RB^1; pre-reads tile
    // TS (k0) at P4. Gates: vmcnt(0) at P1 (A-s1 quarters) and P4 (A-s0+B).
#define TILE_STD(RB, TS) do {                                                 \
    BAR(); GATE0();                                                           \
    RD_A(aQ, RB, 4, 0); RD_B(bQ, RB, 1);                                      \
    stageB((RB) ^ 1, 0, 0, TS); stageB((RB) ^ 1, 0, 1, TS);                   \
    WAITK8; MM(0, aP, bP);                                                    \
    BAR();                                                                    \
    RD_A(aP, RB, 0, 1);                                                       \
    stageB((RB) ^ 1, 1, 0, TS); stageB((RB) ^ 1, 1, 1, TS);                   \
    WAITK4; MM(4, aQ, bP);                                                    \
    BAR();                                                                    \
    RD_A(aQ, RB, 4, 1);                                                       \
    stageA((RB) ^ 1, 0, 0, TS); stageA((RB) ^ 1, 1, 0, TS);                   \
    WAITK4; MM(0, aP, bQ);                                                    \
    BAR(); GATE0();                                                           \
    RD_A(aP, (RB) ^ 1, 0, 0); RD_B(bP, (RB) ^ 1, 0);                          \
    stageA((RB) ^ 1, 0, 1, TS); stageA((RB) ^ 1, 1, 1, TS);                   \
    WAITK8; MM(4, aQ, bQ);                                                    \
} while (0)

    // prologue: stage tile0 into buf0, drain, pre-read (tile0, k0)
    stageB(0, 0, 0, 0); stageB(0, 0, 1, 0); stageB(0, 1, 0, 0); stageB(0, 1, 1, 0);
    stageA(0, 0, 0, 0); stageA(0, 1, 0, 0); stageA(0, 0, 1, 0); stageA(0, 1, 1, 0);
    GATE0();
    BAR();
    RD_A(aP, 0, 0, 0); RD_B(bP, 0, 0);

    for (int i = 0; i < 31; i++) {
        TILE_STD(0, 2 * i + 1);   // tile 2i   (buf0), stages 2i+1
        TILE_STD(1, 2 * i + 2);   // tile 2i+1 (buf1), stages 2i+2
    }
    TILE_STD(0, 63);              // tile 62 (buf0), stages 63

    // tile 63 (buf1): no staging, no next-tile pre-read
    BAR(); GATE0();
    RD_A(aQ, 1, 4, 0); RD_B(bQ, 1, 1);
    WAITK8; MM(0, aP, bP);
    BAR();
    RD_A(aP, 1, 0, 1);
    WAITK4; MM(4, aQ, bP);
    BAR();
    RD_A(aQ, 1, 4, 1);
    WAITK4; MM(0, aP, bQ);
    BAR();
    WAITK0;
    MM(4, aQ, bQ);

    // ================= fused GLU epilogue =================
    __syncthreads();  // all loads drained / reads waited; LDS reusable
    u16* YT = &lds[0][0][0][0];  // [4 batch][256 v][64 c] bf16, 16B-granule swizzled

    // stage 1: acc -> YT
#pragma unroll
    for (int m = 0; m < 8; m++) {
        int bi = wr * 2 + (m >> 2);
        int c0 = (m & 3) * 16 + (lane >> 4) * 4;
#pragma unroll
        for (int n = 0; n < 4; n++) {
            int v = wc * 64 + n * 16 + (lane & 15);
            ushort4 pk;
            pk.x = f2b(acc[m][n][0]); pk.y = f2b(acc[m][n][1]);
            pk.z = f2b(acc[m][n][2]); pk.w = f2b(acc[m][n][3]);
            int addr = bi * 16384 + v * 64 + (((c0 >> 3) ^ (v & 7)) << 3) + (c0 & 7);
            *(ushort4*)&YT[addr] = pk;
        }
    }
    __syncthreads();

    // stage 2: P[f][v] = GLU(W^T Y + bias); weights hoisted out of vq loop
    const int bi2 = wid >> 1, h = wid & 1;
    const u16* Wl = Wt + (size_t)(win * 3 + ks) * 8192;
    u16* Pz = P + (size_t)z * 2048 * nout;
    bf16x8 aw[8][2];
#pragma unroll
    for (int fi = 0; fi < 8; fi++)
#pragma unroll
        for (int kk = 0; kk < 2; kk++)
            aw[fi][kk] = *(const bf16x8*)&Wl[(fi * 16 + (lane & 15)) * 64 + kk * 32 + (lane >> 4) * 8];
#pragma unroll
    for (int vq = 0; vq < 2; vq++) {
        f32x4 acc2[8][4] = {};
        bf16x8 bq2[4][2];
#pragma unroll
        for (int nt = 0; nt < 4; nt++) {
            int v = h * 128 + vq * 64 + nt * 16 + (lane & 15);
#pragma unroll
            for (int kk = 0; kk < 2; kk++) {
                int g = kk * 4 + (lane >> 4);
                bq2[nt][kk] = *(const bf16x8*)&YT[bi2 * 16384 + v * 64 + ((g ^ (v & 7)) << 3)];
            }
        }
#pragma unroll
        for (int fi = 0; fi < 8; fi++)
#pragma unroll
            for (int nt = 0; nt < 4; nt++)
#pragma unroll
                for (int kk = 0; kk < 2; kk++)
                    acc2[fi][nt] = __builtin_amdgcn_mfma_f32_16x16x32_bf16(
                        aw[fi][kk], bq2[nt][kk], acc2[fi][nt], 0, 0, 0);
#pragma unroll
        for (int fi = 0; fi < 4; fi++) {
#pragma unroll
            for (int j = 0; j < 4; j++) {
                int f = fi * 16 + (lane >> 4) * 4 + j;
                float b1 = biasSm[f], b2v = biasSm[f + 64];
#pragma unroll
                for (int nt = 0; nt < 4; nt++) {
                    float g1 = acc2[fi][nt][j] + b1;
                    float g2 = acc2[fi + 4][nt][j] + b2v;
                    float val = g1 * fast_sigmoid(g2);
                    int row = rowBase + bi2 * 64 + f;
                    int col = colBase + h * 128 + vq * 64 + nt * 16 + (lane & 15);
                    Pz[(size_t)row * nout + col] = f2b(val);
                }
            }
        }
    }
#undef RD_A
#undef RD_B
#undef MM
#undef TILE_STD
}

// ---------------------------------------------------------------------------
// final: out[b,win,n,f] += max(P1mid, P2mid, P3)
// ---------------------------------------------------------------------------
__global__ void final_add(const u16* __restrict__ P1, const u16* __restrict__ P2,
                          const u16* __restrict__ P3, float* __restrict__ out, int win0) {
    const int n0 = blockIdx.x * 64, b = blockIdx.y, z = blockIdx.z;
    const int win = win0 + z;
    const int tid = threadIdx.x;
    __shared__ float tl[64][65];
    {
        int f = tid >> 2, q = tid & 3;
        size_t o12 = ((size_t)z * 2048 + b * 64 + f) * 4096 + 1024 + n0 + q * 16;
        size_t o3  = ((size_t)z * 2048 + b * 64 + f) * 1024 + n0 + q * 16;
#pragma unroll
        for (int i = 0; i < 16; i += 4) {
            uint2 a  = *(const uint2*)&P1[o12 + i];
            uint2 c2 = *(const uint2*)&P2[o12 + i];
            uint2 d  = *(const uint2*)&P3[o3 + i];
            u32 av[4] = {a.x & 0xffffu, a.x >> 16, a.y & 0xffffu, a.y >> 16};
            u32 bv[4] = {c2.x & 0xffffu, c2.x >> 16, c2.y & 0xffffu, c2.y >> 16};
            u32 dv[4] = {d.x & 0xffffu, d.x >> 16, d.y & 0xffffu, d.y >> 16};
#pragma unroll
            for (int jj = 0; jj < 4; jj++)
                tl[q * 16 + i + jj][f] = fmaxf(fmaxf(b2f(av[jj]), b2f(bv[jj])), b2f(dv[jj]));
        }
    }
    __syncthreads();
    {
        int n = tid >> 2, q = tid & 3;
        size_t oo = ((size_t)(b * 9 + win) * 1024 + n0 + n) * 64 + q * 16;
#pragma unroll
        for (int i = 0; i < 16; i += 4) {
            float4 cur = *(const float4*)&out[oo + i];
            cur.x += tl[n][q * 16 + i + 0];
            cur.y += tl[n][q * 16 + i + 1];
            cur.z += tl[n][q * 16 + i + 2];
            cur.w += tl[n][q * 16 + i + 3];
            *(float4*)&out[oo + i] = cur;
        }
    }
}

// ---------------------------------------------------------------------------
extern "C" void kernel_launch(void* const* d_in, const int* in_sizes, int n_in,
                              void* d_out, int out_size, void* d_ws, size_t ws_size,
                              hipStream_t stream) {
    const float* data = (const float*)d_in[0];
    const float* adj  = (const float*)d_in[1];
    const float* temb = (const float*)d_in[2];
    const float* semb = (const float*)d_in[3];
    const float* cwl  = (const float*)d_in[4];
    const float* cbl  = (const float*)d_in[5];
    const float* cwr  = (const float*)d_in[6];
    const float* cbr  = (const float*)d_in[7];
    const float* fcw  = (const float*)d_in[8];
    const float* fcb  = (const float*)d_in[9];
    float* out = (float*)d_out;

    char* p = (char*)d_ws;
    auto alloc = [&](size_t bytes) -> char* {
        char* r = p;
        p += (bytes + 255) & ~(size_t)255;
        return r;
    };
    const size_t SZ_XT  = 2048UL * 12288 * 2;
    const size_t SZ_XN  = 32UL * 12 * 1024 * 64 * 2;
    const size_t SZ_ADJ = 4096UL * 4096 * 2;
    const size_t SZ_WT  = 27UL * 128 * 64 * 2;
    const size_t SZ_WC  = 128UL * 128 * 2;
    const size_t SZ_P12 = 2048UL * 4096 * 2;  // 16 MiB
    const size_t SZ_P3  = 2048UL * 1024 * 2;  //  4 MiB
    u16* XT   = (u16*)alloc(SZ_XT);
    u16* adjb = (u16*)alloc(SZ_ADJ);
    u16* Wt   = (u16*)alloc(SZ_WT);
    u16* Wc   = (u16*)alloc(SZ_WC);

    char* winBase = p;
    size_t avail = ws_size - (size_t)(winBase - (char*)d_ws);
    const size_t perwin = 2 * SZ_P12 + SZ_P3 + 3 * 256;
    int cap = (int)(avail / perwin);
    if (cap > 9) cap = 9;
    if (cap < 1) cap = 1;
    u16* P1 = (u16*)alloc((size_t)cap * SZ_P12);
    u16* P2 = (u16*)alloc((size_t)cap * SZ_P12);
    u16* P3 = (u16*)alloc((size_t)cap * SZ_P3);
    // Xn aliases the window-buffer region (dead before first P write)
    u16* Xn = ((size_t)cap * perwin >= SZ_XN + 256) ? (u16*)winBase : (u16*)alloc(SZ_XN);

    cvt_f32_bf16<<<4096, 256, 0, stream>>>(adj, adjb, 4096 * 4096);
    prep_x<<<dim3(16, 12, 32), 256, 0, stream>>>(data, temb, semb, Xn, XT);
    prep_w<<<28, 256, 0, stream>>>(fcw, cwl, cwr, Wt, Wc);
    dconv_gemm<<<dim3(8, 9, 32), 256, 0, stream>>>(Xn, Wc, cbl, cbr, out);

    // balanced window groups
    int ngroups = (9 + cap - 1) / cap;
    int gbase = 9 / ngroups, grem = 9 % ngroups;
    int w0 = 0;
    for (int g = 0; g < ngroups; g++) {
        int cw = gbase + (g < grem ? 1 : 0);
        agg_gemm8<0><<<dim3(16, 8, cw), 512, 0, stream>>>(XT, adjb, Wt, fcb, P1, w0, 0, 4096, 0);
        agg_gemm8<1><<<dim3(16, 8, cw), 512, 0, stream>>>(P1, adjb, Wt, fcb, P2, w0, 0, 4096, 1);
        agg_gemm8<1><<<dim3(4, 8, cw), 512, 0, stream>>>(P2, adjb, Wt, fcb, P3, w0, 1024, 1024, 2);
        final_add<<<dim3(16, 32, cw), 256, 0, stream>>>(P1, P2, P3, out, w0);
        w0 += cw;
    }
}

// Round 7
// 1617.968 us; speedup vs baseline: 1.1046x; 1.1046x over previous
//
#include <hip/hip_runtime.h>
#include <math.h>

typedef unsigned short u16;
typedef unsigned int   u32;
typedef __attribute__((ext_vector_type(8))) short bf16x8;
typedef __attribute__((ext_vector_type(4))) float f32x4;

typedef const void __attribute__((address_space(1))) gv1_t;
typedef void       __attribute__((address_space(3))) lv3_t;
#define GLL(g, l) __builtin_amdgcn_global_load_lds((gv1_t*)(g), (lv3_t*)(l), 16, 0, 0)

__device__ __forceinline__ u16 f2b(float x) {
    union { float f; u32 u; } v; v.f = x;
    u32 r = v.u + 0x7FFFu + ((v.u >> 16) & 1u);
    return (u16)(r >> 16);
}
__device__ __forceinline__ float b2f(u32 x) {
    union { u32 u; float f; } v; v.u = x << 16;
    return v.f;
}
__device__ __forceinline__ float fast_sigmoid(float x) {
    return __builtin_amdgcn_rcpf(1.0f + __builtin_amdgcn_exp2f(-x * 1.44269504f));
}
__device__ __forceinline__ float fast_tanh(float x) {
    return 2.0f * __builtin_amdgcn_rcpf(1.0f + __builtin_amdgcn_exp2f(-x * 2.88539008f)) - 1.0f;
}

// ---------------------------------------------------------------------------
// prep: f32 -> bf16 convert (adj)
// ---------------------------------------------------------------------------
__global__ void cvt_f32_bf16(const float* __restrict__ a, u16* __restrict__ o, int n) {
    for (int i = (blockIdx.x * 256 + threadIdx.x) * 4; i < n; i += gridDim.x * 256 * 4) {
        float4 v = *(const float4*)&a[i];
        uint2 pk;
        pk.x = (u32)f2b(v.x) | ((u32)f2b(v.y) << 16);
        pk.y = (u32)f2b(v.z) | ((u32)f2b(v.w) << 16);
        *(uint2*)&o[i] = pk;
    }
}

// ---------------------------------------------------------------------------
// prep: x = data + temb + semb; write Xn [b][t][n][c] bf16 and XT [(b,c)][t*1024+n]
// ---------------------------------------------------------------------------
__global__ void prep_x(const float* __restrict__ data, const float* __restrict__ temb,
                       const float* __restrict__ semb, u16* __restrict__ Xn, u16* __restrict__ XT) {
    const int n0 = blockIdx.x * 64, t = blockIdx.y, b = blockIdx.z;
    const int tid = threadIdx.x;
    __shared__ u16 lt[64][66];
#pragma unroll
    for (int p = 0; p < 4; p++) {
        int n = p * 16 + (tid >> 4);
        int c = (tid & 15) * 4;
        size_t gi = ((size_t)(b * 12 + t) * 1024 + n0 + n) * 64 + c;
        float4 v  = *(const float4*)&data[gi];
        float4 tv = *(const float4*)&temb[t * 64 + c];
        float4 sv = *(const float4*)&semb[(n0 + n) * 64 + c];
        u16 u0 = f2b(v.x + tv.x + sv.x);
        u16 u1 = f2b(v.y + tv.y + sv.y);
        u16 u2 = f2b(v.z + tv.z + sv.z);
        u16 u3 = f2b(v.w + tv.w + sv.w);
        uint2 pk; pk.x = (u32)u0 | ((u32)u1 << 16); pk.y = (u32)u2 | ((u32)u3 << 16);
        *(uint2*)&Xn[gi] = pk;
        lt[n][c + 0] = u0; lt[n][c + 1] = u1; lt[n][c + 2] = u2; lt[n][c + 3] = u3;
    }
    __syncthreads();
    const int c = tid >> 2, q = tid & 3;
    u16 u[16];
#pragma unroll
    for (int i = 0; i < 16; i++) u[i] = lt[q * 16 + i][c];
    size_t xo = ((size_t)(b * 64 + c)) * 12288 + (size_t)t * 1024 + n0 + q * 16;
    uint4 p0, p1;
    p0.x = (u32)u[0] | ((u32)u[1] << 16);  p0.y = (u32)u[2] | ((u32)u[3] << 16);
    p0.z = (u32)u[4] | ((u32)u[5] << 16);  p0.w = (u32)u[6] | ((u32)u[7] << 16);
    p1.x = (u32)u[8] | ((u32)u[9] << 16);  p1.y = (u32)u[10] | ((u32)u[11] << 16);
    p1.z = (u32)u[12] | ((u32)u[13] << 16); p1.w = (u32)u[14] | ((u32)u[15] << 16);
    *(uint4*)&XT[xo] = p0;
    *(uint4*)&XT[xo + 8] = p1;
}

// ---------------------------------------------------------------------------
// prep: fc_w [27][64][128] -> Wt [27][128][64] bf16 ; conv weights -> Wc bf16
// ---------------------------------------------------------------------------
__global__ void prep_w(const float* __restrict__ fcw, const float* __restrict__ cwl,
                       const float* __restrict__ cwr, u16* __restrict__ Wt, u16* __restrict__ Wc) {
    const int blk = blockIdx.x, tid = threadIdx.x;
    if (blk < 27) {
        const float* src = fcw + (size_t)blk * 64 * 128;
        u16* dst = Wt + (size_t)blk * 128 * 64;
        for (int e = tid; e < 8192; e += 256) {
            int c = e >> 7, f = e & 127;
            dst[f * 64 + c] = f2b(src[c * 128 + f]);
        }
    } else {
        for (int e = tid; e < 16384; e += 256) {
            int o = e >> 7, k = e & 127;
            float v = (o < 64) ? cwl[(o * 64 + (k & 63)) * 2 + (k >> 6)]
                               : cwr[((o - 64) * 64 + (k & 63)) * 2 + (k >> 6)];
            Wc[o * 128 + k] = f2b(v);
        }
    }
}

// ---------------------------------------------------------------------------
// gated dilated conv as GEMM (unchanged)
// ---------------------------------------------------------------------------
__global__ __launch_bounds__(256) void dconv_gemm(
    const u16* __restrict__ Xn, const u16* __restrict__ Wc,
    const float* __restrict__ cbl, const float* __restrict__ cbr,
    float* __restrict__ out) {
    const int n0 = blockIdx.x * 128, t = blockIdx.y, b = blockIdx.z;
    const int tid = threadIdx.x, lane = tid & 63, wid = tid >> 6;
    __shared__ u16 alds[2][128 * 32];
    const u16* base0 = Xn + (size_t)(b * 12 + t) * 1024 * 64;
    const u16* base3 = Xn + (size_t)(b * 12 + t + 3) * 1024 * 64;

    auto stage = [&](int buf, int kt) {
        int k0 = kt * 32;
#pragma unroll
        for (int q = 0; q < 2; q++) {
            int r = wid * 32 + q * 16 + (lane >> 2);
            int k = k0 + (lane & 3) * 8;
            const u16* gs = (k < 64) ? base0 + (size_t)(n0 + r) * 64 + k
                                     : base3 + (size_t)(n0 + r) * 64 + (k - 64);
            GLL(gs, &alds[buf][(wid * 32 + q * 16) * 32]);
        }
    };

    f32x4 acc[2][8] = {};
    stage(0, 0);
    __syncthreads();
    const int a_off = (wid * 32 + (lane & 15)) * 32 + (lane >> 4) * 8;
    for (int kt = 0; kt < 4; kt++) {
        int cur = kt & 1;
        if (kt < 3) stage(cur ^ 1, kt + 1);
        bf16x8 af[2];
#pragma unroll
        for (int m = 0; m < 2; m++) af[m] = *(const bf16x8*)&alds[cur][a_off + m * 16 * 32];
#pragma unroll
        for (int n = 0; n < 8; n++) {
            bf16x8 bq = *(const bf16x8*)&Wc[(n * 16 + (lane & 15)) * 128 + kt * 32 + (lane >> 4) * 8];
#pragma unroll
            for (int m = 0; m < 2; m++)
                acc[m][n] = __builtin_amdgcn_mfma_f32_16x16x32_bf16(af[m], bq, acc[m][n], 0, 0, 0);
        }
        __syncthreads();
    }
#pragma unroll
    for (int m = 0; m < 2; m++) {
#pragma unroll
        for (int n = 0; n < 4; n++) {
            int fp = n * 16 + (lane & 15);
            float b1 = cbl[fp], b2 = cbr[fp];
#pragma unroll
            for (int j = 0; j < 4; j++) {
                int row = wid * 32 + m * 16 + (lane >> 4) * 4 + j;
                float gl = acc[m][n][j] + b1;
                float gr = acc[m][n + 4][j] + b2;
                out[((size_t)(b * 9 + t) * 1024 + n0 + row) * 64 + fp] =
                    fast_sigmoid(gl) * fast_tanh(gr);
            }
        }
    }
}

// ---------------------------------------------------------------------------
// v7 agg GEMM: 256x128 tile, BK=32, 8 waves (wave tile 64x64), 2 blocks/CU.
// K-loop LDS 48KB (dbuf), epilogue reuses 64KB. Swizzle: 16B-chunk
// phys = c ^ ((r>>1)&3), both sides (2-way conflict = free).
// Per tile: BAR; 8 ds_read; lgkm(0); BAR; 3 GLL (next+1 tile -> read buf);
// 16 MFMA; vmcnt(3). Gate-before-next-barrier publishes staged data.
// Fused GLU epilogue: acc -> YT[4][128][64] -> W^T Y GLU -> P.
// ---------------------------------------------------------------------------
#define SCB() __builtin_amdgcn_sched_barrier(0)
#define BARR() do { SCB(); __builtin_amdgcn_s_barrier(); SCB(); } while (0)
#define WAITK0 do { asm volatile("s_waitcnt lgkmcnt(0)" ::: "memory"); SCB(); } while (0)
#define GATE3 do { SCB(); asm volatile("s_waitcnt vmcnt(3)" ::: "memory"); SCB(); } while (0)
#define GATEZ do { SCB(); asm volatile("s_waitcnt vmcnt(0)" ::: "memory"); SCB(); } while (0)

template <int STAGE>
__global__ __launch_bounds__(512, 4) void agg_gemm7(
    const u16* __restrict__ A, const u16* __restrict__ Bt,
    const u16* __restrict__ Wt, const float* __restrict__ fcb,
    u16* __restrict__ P, int win0, int vbase, int nout, int ks) {
    const int tid = threadIdx.x, lane = tid & 63, wid = tid >> 6;
    const int wr = wid >> 1, wc = wid & 1;
    const int bx = blockIdx.x, by = blockIdx.y, z = blockIdx.z;
    const int rowBase = by * 256, colBase = bx * 128;
    const int win = win0 + z;
    __shared__ u16 lds[32768];      // 64 KiB: K-loop uses [2][12288], epilogue all
    __shared__ float biasSm[128];
    biasSm[tid & 127] = fcb[(win * 3 + ks) * 128 + (tid & 127)];
    const u16* Az = (STAGE == 0) ? (A + (size_t)win * 1024)
                                 : (A + (size_t)z * 2048 * 4096);
    const size_t strideA = (STAGE == 0) ? 12288 : 4096;

    // staging: 3 GLL per tile (A: 2x128 rows, B: 1x128 rows), inverse swizzle
    const int r_st = (lane >> 2);                    // row within 16-row wave slice
    const int sc_st = 8 * ((lane & 3) ^ ((r_st >> 1) & 3));  // swizzled k halfword

    auto stageA = [&](int buf, int s, int kt) {
        int r_l = s * 128 + wid * 16 + r_st;
        GLL(Az + (size_t)(rowBase + r_l) * strideA + kt * 32 + sc_st,
            &lds[buf * 12288 + (s * 128 + wid * 16) * 32]);
    };
    auto stageB = [&](int buf, int kt) {
        int r_l = wid * 16 + r_st;
        GLL(Bt + (size_t)(vbase + colBase + r_l) * 4096 + kt * 32 + sc_st,
            &lds[buf * 12288 + 8192 + (wid * 16) * 32]);
    };

    f32x4 acc[4][4] = {};
    bf16x8 aF[4], bF[4];

#define RD_AB(buf)                                                            \
    _Pragma("unroll") for (int mm = 0; mm < 4; mm++) {                        \
        int r = wr * 64 + mm * 16 + (lane & 15);                              \
        aF[mm] = *(const bf16x8*)&lds[(buf) * 12288 + r * 32 +                \
                                      (((lane >> 4) ^ ((r >> 1) & 3)) << 3)]; \
    }                                                                         \
    _Pragma("unroll") for (int nn = 0; nn < 4; nn++) {                        \
        int r = wc * 64 + nn * 16 + (lane & 15);                              \
        bF[nn] = *(const bf16x8*)&lds[(buf) * 12288 + 8192 + r * 32 +         \
                                      (((lane >> 4) ^ ((r >> 1) & 3)) << 3)]; \
    }
#define MFMA16()                                                              \
    __builtin_amdgcn_s_setprio(1);                                            \
    _Pragma("unroll") for (int mm = 0; mm < 4; mm++)                          \
    _Pragma("unroll") for (int nn = 0; nn < 4; nn++)                          \
        acc[mm][nn] = __builtin_amdgcn_mfma_f32_16x16x32_bf16(                \
            aF[mm], bF[nn], acc[mm][nn], 0, 0, 0);                            \
    __builtin_amdgcn_s_setprio(0);

#define TILE7(RB, T2S) do {                                                   \
    BARR();                                                                   \
    RD_AB(RB);                                                                \
    WAITK0;                                                                   \
    BARR();                                                                   \
    stageA(RB, 0, T2S); stageA(RB, 1, T2S); stageB(RB, T2S);                  \
    SCB();                                                                    \
    MFMA16();                                                                 \
    GATE3;                                                                    \
} while (0)

    // prologue: tiles 0,1 -> bufs 0,1; drain tile0 (vmcnt(3) leaves tile1)
    stageA(0, 0, 0); stageA(0, 1, 0); stageB(0, 0);
    stageA(1, 0, 1); stageA(1, 1, 1); stageB(1, 1);
    GATE3;

    for (int t = 0; t < 126; t += 2) {
        TILE7(0, t + 2);
        TILE7(1, t + 3);
    }
    // tile 126 (buf0): no staging; drain everything for tile 127
    BARR();
    RD_AB(0);
    WAITK0;
    BARR();
    MFMA16();
    GATEZ;
    // tile 127 (buf1)
    BARR();
    RD_AB(1);
    WAITK0;
    MFMA16();

    // ================= fused GLU epilogue =================
    __syncthreads();  // all reads done; LDS fully reusable (64KB YT)
    // stage 1: acc -> YT[4 bat][128 v][64 c], 16B-chunk swizzled by (v&7)
#pragma unroll
    for (int mm = 0; mm < 4; mm++) {
        int c0 = mm * 16 + (lane >> 4) * 4;
#pragma unroll
        for (int nn = 0; nn < 4; nn++) {
            int v = wc * 64 + nn * 16 + (lane & 15);
            ushort4 pk;
            pk.x = f2b(acc[mm][nn][0]); pk.y = f2b(acc[mm][nn][1]);
            pk.z = f2b(acc[mm][nn][2]); pk.w = f2b(acc[mm][nn][3]);
            int addr = (wr * 128 + v) * 64 + (((c0 >> 3) ^ (v & 7)) << 3) + (c0 & 7);
            *(ushort4*)&lds[addr] = pk;
        }
    }
    __syncthreads();

    // stage 2: P[(b,f)][v] = GLU(W^T Y + bias)
    const int bat = wid >> 1, fh = wid & 1;
    const u16* Wl = Wt + (size_t)(win * 3 + ks) * 8192;
    u16* Pz = P + (size_t)z * 2048 * nout;
    bf16x8 aw[4][2];
#pragma unroll
    for (int p = 0; p < 4; p++) {
        int mt = (p & 1) + fh * 2 + (p >> 1) * 4;
#pragma unroll
        for (int kk = 0; kk < 2; kk++)
            aw[p][kk] = *(const bf16x8*)&Wl[(mt * 16 + (lane & 15)) * 64 + kk * 32 + (lane >> 4) * 8];
    }
#pragma unroll
    for (int vp = 0; vp < 4; vp++) {
        f32x4 acc2[4][2] = {};
        bf16x8 bq2[2][2];
#pragma unroll
        for (int nt = 0; nt < 2; nt++) {
            int v = vp * 32 + nt * 16 + (lane & 15);
#pragma unroll
            for (int kk = 0; kk < 2; kk++) {
                int ch = kk * 4 + (lane >> 4);
                bq2[nt][kk] = *(const bf16x8*)&lds[(bat * 128 + v) * 64 + ((ch ^ (v & 7)) << 3)];
            }
        }
#pragma unroll
        for (int p = 0; p < 4; p++)
#pragma unroll
            for (int nt = 0; nt < 2; nt++)
#pragma unroll
                for (int kk = 0; kk < 2; kk++)
                    acc2[p][nt] = __builtin_amdgcn_mfma_f32_16x16x32_bf16(
                        aw[p][kk], bq2[nt][kk], acc2[p][nt], 0, 0, 0);
#pragma unroll
        for (int p = 0; p < 2; p++) {
            int mt = (p & 1) + fh * 2;
#pragma unroll
            for (int j = 0; j < 4; j++) {
                int f = mt * 16 + (lane >> 4) * 4 + j;
                float b1 = biasSm[f], b2v = biasSm[f + 64];
#pragma unroll
                for (int nt = 0; nt < 2; nt++) {
                    float g1 = acc2[p][nt][j] + b1;
                    float g2 = acc2[p + 2][nt][j] + b2v;
                    float val = g1 * fast_sigmoid(g2);
                    int row = rowBase + bat * 64 + f;
                    int col = colBase + vp * 32 + nt * 16 + (lane & 15);
                    Pz[(size_t)row * nout + col] = f2b(val);
                }
            }
        }
    }
#undef RD_AB
#undef MFMA16
#undef TILE7
}

// ---------------------------------------------------------------------------
// final: out[b,win,n,f] += max(P1mid, P2mid, P3)
// ---------------------------------------------------------------------------
__global__ void final_add(const u16* __restrict__ P1, const u16* __restrict__ P2,
                          const u16* __restrict__ P3, float* __restrict__ out, int win0) {
    const int n0 = blockIdx.x * 64, b = blockIdx.y, z = blockIdx.z;
    const int win = win0 + z;
    const int tid = threadIdx.x;
    __shared__ float tl[64][65];
    {
        int f = tid >> 2, q = tid & 3;
        size_t o12 = ((size_t)z * 2048 + b * 64 + f) * 4096 + 1024 + n0 + q * 16;
        size_t o3  = ((size_t)z * 2048 + b * 64 + f) * 1024 + n0 + q * 16;
#pragma unroll
        for (int i = 0; i < 16; i += 4) {
            uint2 a  = *(const uint2*)&P1[o12 + i];
            uint2 c2 = *(const uint2*)&P2[o12 + i];
            uint2 d  = *(const uint2*)&P3[o3 + i];
            u32 av[4] = {a.x & 0xffffu, a.x >> 16, a.y & 0xffffu, a.y >> 16};
            u32 bv[4] = {c2.x & 0xffffu, c2.x >> 16, c2.y & 0xffffu, c2.y >> 16};
            u32 dv[4] = {d.x & 0xffffu, d.x >> 16, d.y & 0xffffu, d.y >> 16};
#pragma unroll
            for (int jj = 0; jj < 4; jj++)
                tl[q * 16 + i + jj][f] = fmaxf(fmaxf(b2f(av[jj]), b2f(bv[jj])), b2f(dv[jj]));
        }
    }
    __syncthreads();
    {
        int n = tid >> 2, q = tid & 3;
        size_t oo = ((size_t)(b * 9 + win) * 1024 + n0 + n) * 64 + q * 16;
#pragma unroll
        for (int i = 0; i < 16; i += 4) {
            float4 cur = *(const float4*)&out[oo + i];
            cur.x += tl[n][q * 16 + i + 0];
            cur.y += tl[n][q * 16 + i + 1];
            cur.z += tl[n][q * 16 + i + 2];
            cur.w += tl[n][q * 16 + i + 3];
            *(float4*)&out[oo + i] = cur;
        }
    }
}

// ---------------------------------------------------------------------------
extern "C" void kernel_launch(void* const* d_in, const int* in_sizes, int n_in,
                              void* d_out, int out_size, void* d_ws, size_t ws_size,
                              hipStream_t stream) {
    const float* data = (const float*)d_in[0];
    const float* adj  = (const float*)d_in[1];
    const float* temb = (const float*)d_in[2];
    const float* semb = (const float*)d_in[3];
    const float* cwl  = (const float*)d_in[4];
    const float* cbl  = (const float*)d_in[5];
    const float* cwr  = (const float*)d_in[6];
    const float* cbr  = (const float*)d_in[7];
    const float* fcw  = (const float*)d_in[8];
    const float* fcb  = (const float*)d_in[9];
    float* out = (float*)d_out;

    char* p = (char*)d_ws;
    auto alloc = [&](size_t bytes) -> char* {
        char* r = p;
        p += (bytes + 255) & ~(size_t)255;
        return r;
    };
    const size_t SZ_XT  = 2048UL * 12288 * 2;     // 48 MiB
    const size_t SZ_XN  = 32UL * 12 * 1024 * 64 * 2;
    const size_t SZ_ADJ = 4096UL * 4096 * 2;      // 32 MiB
    const size_t SZ_WT  = 27UL * 128 * 64 * 2;
    const size_t SZ_WC  = 128UL * 128 * 2;
    const size_t SZ_P12 = 2048UL * 4096 * 2;      // 16 MiB
    const size_t SZ_P3  = 2048UL * 1024 * 2;      //  4 MiB
    u16* XT   = (u16*)alloc(SZ_XT);
    u16* adjb = (u16*)alloc(SZ_ADJ);
    u16* Wt   = (u16*)alloc(SZ_WT);
    u16* Wc   = (u16*)alloc(SZ_WC);
    size_t fixed = (size_t)(p - (char*)d_ws);

    bool single = (fixed + 18 * SZ_P12 + 512 <= ws_size);
    if (single) {
        // single z=9 group: P3 aliases XT (dead after agg0), Xn aliases P2
        u16* P1 = (u16*)alloc(9 * SZ_P12);
        u16* P2 = (u16*)alloc(9 * SZ_P12);
        u16* P3 = XT;     // 36 MiB <= 48 MiB, XT last read by agg0
        u16* Xn = P2;     // 48 MiB <= 144 MiB, Xn dead before agg1 writes P2

        cvt_f32_bf16<<<4096, 256, 0, stream>>>(adj, adjb, 4096 * 4096);
        prep_x<<<dim3(16, 12, 32), 256, 0, stream>>>(data, temb, semb, Xn, XT);
        prep_w<<<28, 256, 0, stream>>>(fcw, cwl, cwr, Wt, Wc);
        dconv_gemm<<<dim3(8, 9, 32), 256, 0, stream>>>(Xn, Wc, cbl, cbr, out);

        agg_gemm7<0><<<dim3(32, 8, 9), 512, 0, stream>>>(XT, adjb, Wt, fcb, P1, 0, 0, 4096, 0);
        agg_gemm7<1><<<dim3(32, 8, 9), 512, 0, stream>>>(P1, adjb, Wt, fcb, P2, 0, 0, 4096, 1);
        agg_gemm7<1><<<dim3(8, 8, 9), 512, 0, stream>>>(P2, adjb, Wt, fcb, P3, 0, 1024, 1024, 2);
        final_add<<<dim3(16, 32, 9), 256, 0, stream>>>(P1, P2, P3, out, 0);
    } else {
        char* winBase = p;
        size_t avail = ws_size - (size_t)(winBase - (char*)d_ws);
        const size_t perwin = 2 * SZ_P12 + SZ_P3 + 3 * 256;
        int cap = (int)(avail / perwin);
        if (cap > 9) cap = 9;
        if (cap < 1) cap = 1;
        u16* P1 = (u16*)alloc((size_t)cap * SZ_P12);
        u16* P2 = (u16*)alloc((size_t)cap * SZ_P12);
        u16* P3 = (u16*)alloc((size_t)cap * SZ_P3);
        u16* Xn = ((size_t)cap * perwin >= SZ_XN + 256) ? (u16*)winBase : (u16*)alloc(SZ_XN);

        cvt_f32_bf16<<<4096, 256, 0, stream>>>(adj, adjb, 4096 * 4096);
        prep_x<<<dim3(16, 12, 32), 256, 0, stream>>>(data, temb, semb, Xn, XT);
        prep_w<<<28, 256, 0, stream>>>(fcw, cwl, cwr, Wt, Wc);
        dconv_gemm<<<dim3(8, 9, 32), 256, 0, stream>>>(Xn, Wc, cbl, cbr, out);

        int ngroups = (9 + cap - 1) / cap;
        int gbase = 9 / ngroups, grem = 9 % ngroups;
        int w0 = 0;
        for (int g = 0; g < ngroups; g++) {
            int cw = gbase + (g < grem ? 1 : 0);
            agg_gemm7<0><<<dim3(32, 8, cw), 512, 0, stream>>>(XT, adjb, Wt, fcb, P1, w0, 0, 4096, 0);
            agg_gemm7<1><<<dim3(32, 8, cw), 512, 0, stream>>>(P1, adjb, Wt, fcb, P2, w0, 0, 4096, 1);
            agg_gemm7<1><<<dim3(8, 8, cw), 512, 0, stream>>>(P2, adjb, Wt, fcb, P3, w0, 1024, 1024, 2);
            final_add<<<dim3(16, 32, cw), 256, 0, stream>>>(P1, P2, P3, out, w0);
            w0 += cw;
        }
    }
}